// Round 13
// baseline (36.783 us; speedup 1.0000x reference)
//
#include <hip/hip_runtime.h>

// Problem constants
constexpr int cN1 = 85,  cF1 = 256, cO1 = 200, cE1 = 1360;
constexpr int cN2 = 5625, cF2 = 128, cE2 = 180000;

// deg2: NPART edge-sliced partial LDS histograms (plain-stored, no atomics)
constexpr int NPART = 8;
constexpr int PBINS = 5632;              // >= cN2, 64-aligned
constexpr int EPP   = cE2 / NPART;       // 22500

// g2 aggregation: NS edge slices; each block builds a FULL-range [PBINS][2]
// partial in LDS (branch-free scan), with dinv computed inline from a
// block-local u16 deg table (built from the 8 partials, coalesced).
constexpr int NS  = 90;
constexpr int ESL = cE2 / NS;            // 2000 edges per slice

// Workspace layout (4-byte words) — nothing needs pre-zeroing:
constexpr int OFF_PART  = 0;                         // 8*5632 i32 deg partials
constexpr int OFF_P2    = NPART * PBINS;             // 45056: NS*PBINS*2 f32
constexpr int OFF_DINV1 = OFF_P2 + NS * PBINS * 2;   // 1058816: 85 f32 (+pad)
constexpr int OFF_G1    = OFF_DINV1 + 128;           // 1058944: 17000 f32
constexpr int OFF_H1    = OFF_G1 + cN1 * cO1;        // 1075944: 17000 f32 (x1@W1)
constexpr int OFF_H2    = OFF_H1 + cN1 * cO1;        // 1092944: 11250 f32 raw h2 (even)
// end = 1104194 words ~= 4.42 MB

// ---------------- K1: hist + deg1 + GEMM1 + GEMM2 (role-split, all indep) -------
constexpr int G2_B    = (cN2 + 7) / 8;               // 704
constexpr int K1_GRID = NPART + 1 + cN1 + G2_B;      // 798

__global__ __launch_bounds__(256) void k1_front(
    const float* __restrict__ x1, const float* __restrict__ x2,
    const float* __restrict__ W1, const float* __restrict__ W2,
    const int* __restrict__ ei1, const int* __restrict__ ei2,
    float* __restrict__ ws_f)
{
    int* ws_i = reinterpret_cast<int*>(ws_f);
    int b = blockIdx.x, t = threadIdx.x;

    if (b < NPART) {
        // deg2 partial histogram over edge slice [b*EPP, (b+1)*EPP)
        __shared__ int s_h[PBINS];
        for (int i = t; i < PBINS; i += 256) s_h[i] = 0;
        __syncthreads();
        const int* dstp = ei2 + cE2 + b * EPP;
        #pragma unroll 4
        for (int i = t; i < EPP; i += 256)
            atomicAdd(&s_h[dstp[i]], 1);              // LDS atomic only
        __syncthreads();
        for (int i = t; i < PBINS; i += 256)
            ws_i[OFF_PART + b * PBINS + i] = s_h[i];  // plain store
        return;
    }
    b -= NPART;

    if (b == 0) {
        // deg1 histogram -> dinv1 table (85 nodes)
        __shared__ int s_deg[cN1];
        if (t < cN1) s_deg[t] = 0;
        __syncthreads();
        for (int i = t; i < cE1; i += 256) atomicAdd(&s_deg[ei1[cE1 + i]], 1);
        __syncthreads();
        if (t < cN1) ws_f[OFF_DINV1 + t] = rsqrtf((float)(s_deg[t] + 1));
        return;
    }
    b -= 1;

    if (b < cN1) {
        // GEMM1: h1[b][t] = sum_k x1[b][k] * W1[k][t]  (t < 200)
        if (t < cO1) {
            const float* xr = x1 + b * cF1;           // uniform across block
            float s = 0.f;
            #pragma unroll 32
            for (int k = 0; k < cF1; ++k)
                s = fmaf(xr[k], W1[k * cO1 + t], s);  // coalesced across t
            ws_f[OFF_H1 + b * cO1 + t] = s;
        }
        return;
    }
    b -= cN1;

    // GEMM2: 32-lane group per row; W2 (1 KB) cache-resident; stores RAW h2.
    int row = b * 8 + (t >> 5), l = t & 31;
    if (row < cN2) {
        float4 xv = reinterpret_cast<const float4*>(x2 + row * cF2)[l];
        int kb = l * 4;
        float p0 = xv.x * W2[(kb + 0) * 2 + 0] + xv.y * W2[(kb + 1) * 2 + 0]
                 + xv.z * W2[(kb + 2) * 2 + 0] + xv.w * W2[(kb + 3) * 2 + 0];
        float p1 = xv.x * W2[(kb + 0) * 2 + 1] + xv.y * W2[(kb + 1) * 2 + 1]
                 + xv.z * W2[(kb + 2) * 2 + 1] + xv.w * W2[(kb + 3) * 2 + 1];
        #pragma unroll
        for (int m = 16; m >= 1; m >>= 1) {
            p0 += __shfl_xor(p0, m);
            p1 += __shfl_xor(p1, m);
        }
        if (l == 0)
            reinterpret_cast<float2*>(ws_f + OFF_H2)[row] = make_float2(p0, p1);
    }
}

// ---------------- K2: g1 match-list gather + g2 sliced gather (inline dinv) -----
// roles: [0,85) g1 node blocks | [85, 85+NS) g2 slice blocks
constexpr int K2_GRID = cN1 + NS;   // 175

__global__ __launch_bounds__(256) void k2_gather(
    const int* __restrict__ ei1, const int* __restrict__ ei2,
    float* __restrict__ ws_f)
{
    __shared__ float          s_acc[2 * PBINS];       // 45 KB
    __shared__ unsigned short s_deg[PBINS];           // 11 KB  (deg2, block-local)
    int b = blockIdx.x, t = threadIdx.x;

    if (b < cN1) {
        // graph1 node b: parallel match scan -> LDS list -> register accumulate
        int* s_list = reinterpret_cast<int*>(s_acc);  // [0]=count, [1..]=srcs
        if (t == 0) s_list[0] = 0;
        __syncthreads();
        for (int i = t; i < cE1; i += 256) {          // 6 coalesced iterations
            int d = ei1[cE1 + i];
            if (d == b) {
                int k = atomicAdd(&s_list[0], 1) + 1;
                s_list[k] = ei1[i];
            }
        }
        __syncthreads();
        int cnt = s_list[0];
        if (t < cO1) {
            float acc = 0.f;
            for (int m = 1; m <= cnt; ++m) {          // ~16 iters, indep loads
                int s = s_list[m];
                acc = fmaf(ws_f[OFF_DINV1 + s], ws_f[OFF_H1 + s * cO1 + t], acc);
            }
            float dn = ws_f[OFF_DINV1 + b];
            ws_f[OFF_G1 + b * cO1 + t] =
                dn * (acc + dn * ws_f[OFF_H1 + b * cO1 + t]);
        }
        return;
    }
    int s = b - cN1;
    const int* ws_i = reinterpret_cast<const int*>(ws_f);

    // Build block-local u16 deg table (coalesced; 8-partial sum per node).
    #pragma unroll 2
    for (int n = t; n < cN2; n += 256) {
        int d = 0;
        #pragma unroll
        for (int p = 0; p < NPART; ++p) d += ws_i[OFF_PART + p * PBINS + n];
        s_deg[n] = (unsigned short)d;
    }
    for (int i = t; i < 2 * PBINS; i += 256) s_acc[i] = 0.f;
    __syncthreads();

    // Branch-free int4-batched scan of slice s; dinv[src] inline via LDS deg.
    const int e0 = s * ESL;
    const float2* h2 = reinterpret_cast<const float2*>(ws_f + OFF_H2);
    #pragma unroll
    for (int batch = 0; batch < 2; ++batch) {
        int off = batch * 1024 + t * 4;
        if (off < ESL) {                              // int4 fully valid (4 | ESL)
            int4 s4 = *reinterpret_cast<const int4*>(ei2 + e0 + off);
            int4 d4 = *reinterpret_cast<const int4*>(ei2 + cE2 + e0 + off);
            float2 h0 = h2[s4.x], h1 = h2[s4.y], hh2 = h2[s4.z], h3 = h2[s4.w];
            float v0 = rsqrtf((float)(s_deg[s4.x] + 1));
            float v1 = rsqrtf((float)(s_deg[s4.y] + 1));
            float v2 = rsqrtf((float)(s_deg[s4.z] + 1));
            float v3 = rsqrtf((float)(s_deg[s4.w] + 1));
            atomicAdd(&s_acc[d4.x * 2 + 0], h0.x * v0);
            atomicAdd(&s_acc[d4.x * 2 + 1], h0.y * v0);
            atomicAdd(&s_acc[d4.y * 2 + 0], h1.x * v1);
            atomicAdd(&s_acc[d4.y * 2 + 1], h1.y * v1);
            atomicAdd(&s_acc[d4.z * 2 + 0], hh2.x * v2);
            atomicAdd(&s_acc[d4.z * 2 + 1], hh2.y * v2);
            atomicAdd(&s_acc[d4.w * 2 + 0], h3.x * v3);
            atomicAdd(&s_acc[d4.w * 2 + 1], h3.y * v3);
        }
    }
    __syncthreads();
    float* dst = ws_f + OFF_P2 + s * PBINS * 2;
    for (int i = t; i < 2 * PBINS; i += 256) dst[i] = s_acc[i];   // coalesced
}

// ---------------- K3: parallel partial-reduce + bias + relu + final linear ------
__global__ __launch_bounds__(128) void k3_head(
    const float* __restrict__ ws_f,
    const float* __restrict__ b1, const float* __restrict__ b2,
    const float* __restrict__ Wf, const float* __restrict__ bf,
    float* __restrict__ out)
{
    const int* ws_i = reinterpret_cast<const int*>(ws_f);
    __shared__ float sred[45][2];
    __shared__ float sh[113];
    int r = blockIdx.x, t = threadIdx.x;

    // Phase A: reduce the NS=90 g2 partials; 2 threads per (n,c) target.
    if (t < 90) {
        int j = t >> 1, half = t & 1;
        int f = r * 45 + j, n = f >> 1, c = f & 1;
        const float* base = ws_f + OFF_P2 + n * 2 + c;
        float s = 0.f;
        #pragma unroll 9
        for (int p = half * 45; p < half * 45 + 45; ++p)
            s += base[p * PBINS * 2];
        sred[j][half] = s;
    }
    __syncthreads();

    // Phase B: assemble the 113-wide concat row (bias + relu).
    if (t < 113) {
        float v;
        if (t < 68) {
            int f = r * 68 + t;                       // h1.reshape(250,68) flat
            v = ws_f[OFF_G1 + f] + b1[f % 200];
        } else {
            int j = t - 68;
            int f = r * 45 + j, n = f >> 1, c = f & 1;
            int d = 0;
            #pragma unroll
            for (int p = 0; p < NPART; ++p) d += ws_i[OFF_PART + p * PBINS + n];
            float dv = rsqrtf((float)(d + 1));
            float sum = sred[j][0] + sred[j][1];
            v = dv * sum + dv * dv * ws_f[OFF_H2 + n * 2 + c] + b2[c];
        }
        sh[t] = fmaxf(v, 0.f);
    }
    __syncthreads();

    // Phase C: final 113x5 linear; 5 outputs x 16-lane shuffle groups.
    if (t < 80) {
        int o = t >> 4, l = t & 15;
        float s = 0.f;
        for (int k = l; k < 113; k += 16)
            s = fmaf(sh[k], Wf[k * 5 + o], s);
        #pragma unroll
        for (int m = 8; m >= 1; m >>= 1) s += __shfl_down(s, m, 16);
        if (l == 0) out[r * 5 + o] = s + bf[o];
    }
}

extern "C" void kernel_launch(void* const* d_in, const int* in_sizes, int n_in,
                              void* d_out, int out_size, void* d_ws, size_t ws_size,
                              hipStream_t stream)
{
    const float* x1 = (const float*)d_in[0];
    const float* x2 = (const float*)d_in[1];
    const float* W1 = (const float*)d_in[2];
    const float* b1 = (const float*)d_in[3];
    const float* W2 = (const float*)d_in[4];
    const float* b2 = (const float*)d_in[5];
    const float* Wf = (const float*)d_in[6];
    const float* bf = (const float*)d_in[7];
    const int*   ei1 = (const int*)d_in[8];
    const int*   ei2 = (const int*)d_in[9];
    float* ws_f = (float*)d_ws;
    float* out  = (float*)d_out;

    k1_front<<<K1_GRID, 256, 0, stream>>>(x1, x2, W1, W2, ei1, ei2, ws_f);
    k2_gather<<<K2_GRID, 256, 0, stream>>>(ei1, ei2, ws_f);
    k3_head<<<250, 128, 0, stream>>>(ws_f, b1, b2, Wf, bf, out);
}

// Round 14
// 31.242 us; speedup vs baseline: 1.1774x; 1.1774x over previous
//
#include <hip/hip_runtime.h>

// Problem constants
constexpr int cN1 = 85,  cF1 = 256, cO1 = 200, cE1 = 1360;
constexpr int cN2 = 5625, cF2 = 128, cE2 = 180000;

// deg2: NPART edge-sliced partial LDS histograms (plain-stored, no atomics)
constexpr int NPART = 8;
constexpr int PBINS = 5632;              // >= cN2, 64-aligned
constexpr int EPP   = cE2 / NPART;       // 22500 edges per hist block (16B-aligned base)

// g2 aggregation: NS edge slices; each block builds a FULL-range [PBINS][2]
// partial in LDS (branch-free scan of hs2 = dinv*h2), plain-stored.
constexpr int NS  = 90;
constexpr int ESL = cE2 / NS;            // 2000 edges per slice

// Workspace layout (4-byte words) — nothing needs pre-zeroing:
constexpr int OFF_PART  = 0;                         // 8*5632 i32 deg partials
constexpr int OFF_P2    = NPART * PBINS;             // 45056: NS*PBINS*2 f32
constexpr int OFF_DINV  = OFF_P2 + NS * PBINS * 2;   // 1058816: 5632 f32
constexpr int OFF_HS2   = OFF_DINV + PBINS;          // 1064448: 5632*2 f32 (dinv*h2)
constexpr int OFF_DINV1 = OFF_HS2 + PBINS * 2;       // 1075712: 85 f32 (+pad)
constexpr int OFF_G1    = OFF_DINV1 + 128;           // 1075840: 17000 f32
constexpr int OFF_H1    = OFF_G1 + cN1 * cO1;        // 1092840: 17000 f32 (x1@W1)
// end = 1109840 words ~= 4.44 MB

// ---------------- kA: deg2 partial hists (int4 scan) + dinv1 — 9 blocks ---------
constexpr int KA_GRID = NPART + 1;

__global__ __launch_bounds__(256) void kA_hist(
    const int* __restrict__ ei1, const int* __restrict__ ei2,
    float* __restrict__ ws_f)
{
    int* ws_i = reinterpret_cast<int*>(ws_f);
    int b = blockIdx.x, t = threadIdx.x;

    if (b < NPART) {
        // Partial histogram over edge slice [b*EPP, (b+1)*EPP), int4-batched.
        __shared__ int s_h[PBINS];
        for (int i = t; i < PBINS; i += 256) s_h[i] = 0;
        __syncthreads();
        const int4* dst4 = reinterpret_cast<const int4*>(ei2 + cE2 + b * EPP);
        for (int i = t; i < EPP / 4; i += 256) {      // 5625 int4s -> 22 iters
            int4 d = dst4[i];
            atomicAdd(&s_h[d.x], 1);
            atomicAdd(&s_h[d.y], 1);
            atomicAdd(&s_h[d.z], 1);
            atomicAdd(&s_h[d.w], 1);
        }
        // tail: EPP%4 == 0, none
        __syncthreads();
        for (int i = t; i < PBINS; i += 256)
            ws_i[OFF_PART + b * PBINS + i] = s_h[i];  // plain store
        return;
    }

    // deg1 histogram -> dinv1 table (85 nodes)
    __shared__ int s_deg[cN1];
    if (t < cN1) s_deg[t] = 0;
    __syncthreads();
    for (int i = t; i < cE1; i += 256) atomicAdd(&s_deg[ei1[cE1 + i]], 1);
    __syncthreads();
    if (t < cN1) ws_f[OFF_DINV1 + t] = rsqrtf((float)(s_deg[t] + 1));
}

// ---------------- kB: GEMM1 + GEMM2-fused-with-table (role-split) ---------------
// roles: [0,85) GEMM1 | [85, 85+704) GEMM2 + dinv/hs2 production
constexpr int G2_B    = (cN2 + 7) / 8;     // 704
constexpr int KB_GRID = cN1 + G2_B;        // 789

__global__ __launch_bounds__(256) void kB_gemm(
    const float* __restrict__ x1, const float* __restrict__ x2,
    const float* __restrict__ W1, const float* __restrict__ W2,
    float* __restrict__ ws_f)
{
    const int* ws_i = reinterpret_cast<const int*>(ws_f);
    int b = blockIdx.x, t = threadIdx.x;

    if (b < cN1) {
        // GEMM1: h1[b][t] = sum_k x1[b][k] * W1[k][t]  (t < 200)
        if (t < cO1) {
            const float* xr = x1 + b * cF1;           // uniform across block
            float s = 0.f;
            #pragma unroll 32
            for (int k = 0; k < cF1; ++k)
                s = fmaf(xr[k], W1[k * cO1 + t], s);  // coalesced across t
            ws_f[OFF_H1 + b * cO1 + t] = s;
        }
        return;
    }
    b -= cN1;

    // GEMM2: 32-lane group per row; W2 (1 KB) cache-resident.
    int row = b * 8 + (t >> 5), l = t & 31;
    if (row >= cN2) return;

    float4 xv = reinterpret_cast<const float4*>(x2 + row * cF2)[l];
    int kb = l * 4;
    float p0 = xv.x * W2[(kb + 0) * 2 + 0] + xv.y * W2[(kb + 1) * 2 + 0]
             + xv.z * W2[(kb + 2) * 2 + 0] + xv.w * W2[(kb + 3) * 2 + 0];
    float p1 = xv.x * W2[(kb + 0) * 2 + 1] + xv.y * W2[(kb + 1) * 2 + 1]
             + xv.z * W2[(kb + 2) * 2 + 1] + xv.w * W2[(kb + 3) * 2 + 1];
    #pragma unroll
    for (int m = 16; m >= 1; m >>= 1) {
        p0 += __shfl_xor(p0, m);
        p1 += __shfl_xor(p1, m);
    }
    if (l == 0) {
        int d = 0;
        #pragma unroll
        for (int p = 0; p < NPART; ++p) d += ws_i[OFF_PART + p * PBINS + row];
        float dv = rsqrtf((float)(d + 1));
        ws_f[OFF_DINV + row] = dv;
        reinterpret_cast<float2*>(ws_f + OFF_HS2)[row] =
            make_float2(dv * p0, dv * p1);            // hs2 = dinv * h2
    }
}

// ---------------- kC: g1 match-list gather + g2 full-range sliced gather --------
// roles: [0,85) g1 node blocks | [85, 85+NS) g2 slice blocks
constexpr int KC_GRID = cN1 + NS;   // 175

__global__ __launch_bounds__(256) void kC_gather(
    const int* __restrict__ ei1, const int* __restrict__ ei2,
    float* __restrict__ ws_f)
{
    __shared__ float sm[2 * PBINS];          // 45 KB, shared by both roles
    int b = blockIdx.x, t = threadIdx.x;

    if (b < cN1) {
        // graph1 node b: parallel match scan -> LDS list -> register accumulate
        int* s_list = reinterpret_cast<int*>(sm);     // [0]=count, [1..]=srcs
        if (t == 0) s_list[0] = 0;
        __syncthreads();
        for (int i = t; i < cE1; i += 256) {          // 6 coalesced iterations
            int d = ei1[cE1 + i];
            if (d == b) {
                int k = atomicAdd(&s_list[0], 1) + 1;
                s_list[k] = ei1[i];
            }
        }
        __syncthreads();
        int cnt = s_list[0];
        if (t < cO1) {
            float acc = 0.f;
            for (int m = 1; m <= cnt; ++m) {          // ~16 iters, indep loads
                int s = s_list[m];
                acc = fmaf(ws_f[OFF_DINV1 + s], ws_f[OFF_H1 + s * cO1 + t], acc);
            }
            float dn = ws_f[OFF_DINV1 + b];
            ws_f[OFF_G1 + b * cO1 + t] =
                dn * (acc + dn * ws_f[OFF_H1 + b * cO1 + t]);
        }
        return;
    }
    int s = b - cN1;

    // graph2 slice s: branch-free full-range partial in LDS
    for (int i = t; i < 2 * PBINS; i += 256) sm[i] = 0.f;
    __syncthreads();
    const int e0 = s * ESL;
    #pragma unroll
    for (int batch = 0; batch < 2; ++batch) {
        int off = batch * 1024 + t * 4;
        if (off < ESL) {                              // whole int4 valid (ESL%4==0)
            int4 s4 = *reinterpret_cast<const int4*>(ei2 + e0 + off);
            int4 d4 = *reinterpret_cast<const int4*>(ei2 + cE2 + e0 + off);
            const float2* hs2 = reinterpret_cast<const float2*>(ws_f + OFF_HS2);
            float2 h0 = hs2[s4.x], h1 = hs2[s4.y], h2 = hs2[s4.z], h3 = hs2[s4.w];
            atomicAdd(&sm[d4.x * 2 + 0], h0.x); atomicAdd(&sm[d4.x * 2 + 1], h0.y);
            atomicAdd(&sm[d4.y * 2 + 0], h1.x); atomicAdd(&sm[d4.y * 2 + 1], h1.y);
            atomicAdd(&sm[d4.z * 2 + 0], h2.x); atomicAdd(&sm[d4.z * 2 + 1], h2.y);
            atomicAdd(&sm[d4.w * 2 + 0], h3.x); atomicAdd(&sm[d4.w * 2 + 1], h3.y);
        }
    }
    __syncthreads();
    float* dst = ws_f + OFF_P2 + s * PBINS * 2;
    for (int i = t; i < 2 * PBINS; i += 256) dst[i] = sm[i];   // coalesced stores
}

// ---------------- kD: parallel partial-reduce + bias + relu + final linear ------
__global__ __launch_bounds__(128) void kD_head(
    const float* __restrict__ ws_f,
    const float* __restrict__ b1, const float* __restrict__ b2,
    const float* __restrict__ Wf, const float* __restrict__ bf,
    float* __restrict__ out)
{
    __shared__ float sred[45][2];
    __shared__ float sh[113];
    int r = blockIdx.x, t = threadIdx.x;

    // Phase A: reduce the NS=90 g2 partials; 2 threads per (n,c) target.
    if (t < 90) {
        int j = t >> 1, half = t & 1;
        int f = r * 45 + j, n = f >> 1, c = f & 1;
        const float* base = ws_f + OFF_P2 + n * 2 + c;
        float s = 0.f;
        #pragma unroll 9
        for (int p = half * 45; p < half * 45 + 45; ++p)
            s += base[p * PBINS * 2];
        sred[j][half] = s;
    }
    __syncthreads();

    // Phase B: assemble the 113-wide concat row (bias + relu).
    if (t < 113) {
        float v;
        if (t < 68) {
            int f = r * 68 + t;                       // h1.reshape(250,68) flat
            v = ws_f[OFF_G1 + f] + b1[f % 200];
        } else {
            int j = t - 68;
            int f = r * 45 + j, n = f >> 1, c = f & 1;
            float sum = ws_f[OFF_HS2 + n * 2 + c]     // self loop: dinv*h2
                      + sred[j][0] + sred[j][1];
            v = ws_f[OFF_DINV + n] * sum + b2[c];
        }
        sh[t] = fmaxf(v, 0.f);
    }
    __syncthreads();

    // Phase C: final 113x5 linear; 5 outputs x 16-lane shuffle groups.
    if (t < 80) {
        int o = t >> 4, l = t & 15;
        float s = 0.f;
        for (int k = l; k < 113; k += 16)
            s = fmaf(sh[k], Wf[k * 5 + o], s);
        #pragma unroll
        for (int m = 8; m >= 1; m >>= 1) s += __shfl_down(s, m, 16);
        if (l == 0) out[r * 5 + o] = s + bf[o];
    }
}

extern "C" void kernel_launch(void* const* d_in, const int* in_sizes, int n_in,
                              void* d_out, int out_size, void* d_ws, size_t ws_size,
                              hipStream_t stream)
{
    const float* x1 = (const float*)d_in[0];
    const float* x2 = (const float*)d_in[1];
    const float* W1 = (const float*)d_in[2];
    const float* b1 = (const float*)d_in[3];
    const float* W2 = (const float*)d_in[4];
    const float* b2 = (const float*)d_in[5];
    const float* Wf = (const float*)d_in[6];
    const float* bf = (const float*)d_in[7];
    const int*   ei1 = (const int*)d_in[8];
    const int*   ei2 = (const int*)d_in[9];
    float* ws_f = (float*)d_ws;
    float* out  = (float*)d_out;

    kA_hist<<<KA_GRID, 256, 0, stream>>>(ei1, ei2, ws_f);
    kB_gemm<<<KB_GRID, 256, 0, stream>>>(x1, x2, W1, W2, ws_f);
    kC_gather<<<KC_GRID, 256, 0, stream>>>(ei1, ei2, ws_f);
    kD_head<<<250, 128, 0, stream>>>(ws_f, b1, b2, Wf, bf, out);
}

// Round 15
// 30.904 us; speedup vs baseline: 1.1902x; 1.0109x over previous
//
#include <hip/hip_runtime.h>

// Problem constants
constexpr int cN1 = 85,  cF1 = 256, cO1 = 200, cE1 = 1360;
constexpr int cN2 = 5625, cF2 = 128, cE2 = 180000;

// deg2: NPART edge-sliced partial LDS histograms (plain-stored, no atomics)
constexpr int NPART = 4;
constexpr int PBINS = 5632;              // >= cN2, 64-aligned
constexpr int EPP   = cE2 / NPART;       // 45000 edges per hist block (16B-aligned)

// g2 aggregation: NS edge slices; each block builds a FULL-range [PBINS][2]
// partial in LDS (branch-free int4 scan, dinv inline from u16 LDS deg table).
constexpr int NS  = 90;
constexpr int ESL = cE2 / NS;            // 2000 edges per slice

// Workspace layout (4-byte words) — nothing needs pre-zeroing:
constexpr int OFF_PART  = 0;                         // 4*5632 i32 deg partials
constexpr int OFF_P2    = NPART * PBINS;             // 22528: NS*PBINS*2 f32
constexpr int OFF_DINV1 = OFF_P2 + NS * PBINS * 2;   // 1036288: 85 f32 (+pad)
constexpr int OFF_G1    = OFF_DINV1 + 128;           // 1036416: 17000 f32
constexpr int OFF_H1    = OFF_G1 + cN1 * cO1;        // 1053416: 17000 f32 (x1@W1)
constexpr int OFF_H2    = OFF_H1 + cN1 * cO1;        // 1070416: 11250 f32 raw h2 (even)
// end = 1081666 words ~= 4.33 MB

// ---------------- D1: hist + deg1 + GEMM1 + GEMM2-raw (role-split) --------------
constexpr int G2_B    = (cN2 + 7) / 8;               // 704
constexpr int K1_GRID = NPART + 1 + cN1 + G2_B;      // 794

__global__ __launch_bounds__(256) void k1_front(
    const float* __restrict__ x1, const float* __restrict__ x2,
    const float* __restrict__ W1, const float* __restrict__ W2,
    const int* __restrict__ ei1, const int* __restrict__ ei2,
    float* __restrict__ ws_f)
{
    int* ws_i = reinterpret_cast<int*>(ws_f);
    int b = blockIdx.x, t = threadIdx.x;

    if (b < NPART) {
        // Partial histogram over edge slice [b*EPP, (b+1)*EPP), int4-batched.
        __shared__ int s_h[PBINS];
        for (int i = t; i < PBINS; i += 256) s_h[i] = 0;
        __syncthreads();
        const int4* dst4 = reinterpret_cast<const int4*>(ei2 + cE2 + b * EPP);
        for (int i = t; i < EPP / 4; i += 256) {      // 11250 int4s -> 44 iters
            int4 d = dst4[i];
            atomicAdd(&s_h[d.x], 1);
            atomicAdd(&s_h[d.y], 1);
            atomicAdd(&s_h[d.z], 1);
            atomicAdd(&s_h[d.w], 1);
        }
        __syncthreads();
        for (int i = t; i < PBINS; i += 256)
            ws_i[OFF_PART + b * PBINS + i] = s_h[i];  // plain store
        return;
    }
    b -= NPART;

    if (b == 0) {
        // deg1 histogram -> dinv1 table (85 nodes)
        __shared__ int s_deg[cN1];
        if (t < cN1) s_deg[t] = 0;
        __syncthreads();
        for (int i = t; i < cE1; i += 256) atomicAdd(&s_deg[ei1[cE1 + i]], 1);
        __syncthreads();
        if (t < cN1) ws_f[OFF_DINV1 + t] = rsqrtf((float)(s_deg[t] + 1));
        return;
    }
    b -= 1;

    if (b < cN1) {
        // GEMM1: h1[b][t] = sum_k x1[b][k] * W1[k][t]  (t < 200)
        if (t < cO1) {
            const float* xr = x1 + b * cF1;           // uniform across block
            float s = 0.f;
            #pragma unroll 32
            for (int k = 0; k < cF1; ++k)
                s = fmaf(xr[k], W1[k * cO1 + t], s);  // coalesced across t
            ws_f[OFF_H1 + b * cO1 + t] = s;
        }
        return;
    }
    b -= cN1;

    // GEMM2: 32-lane group per row; W2 (1 KB) cache-resident; stores RAW h2.
    int row = b * 8 + (t >> 5), l = t & 31;
    if (row < cN2) {
        float4 xv = reinterpret_cast<const float4*>(x2 + row * cF2)[l];
        int kb = l * 4;
        float p0 = xv.x * W2[(kb + 0) * 2 + 0] + xv.y * W2[(kb + 1) * 2 + 0]
                 + xv.z * W2[(kb + 2) * 2 + 0] + xv.w * W2[(kb + 3) * 2 + 0];
        float p1 = xv.x * W2[(kb + 0) * 2 + 1] + xv.y * W2[(kb + 1) * 2 + 1]
                 + xv.z * W2[(kb + 2) * 2 + 1] + xv.w * W2[(kb + 3) * 2 + 1];
        #pragma unroll
        for (int m = 16; m >= 1; m >>= 1) {
            p0 += __shfl_xor(p0, m);
            p1 += __shfl_xor(p1, m);
        }
        if (l == 0)
            reinterpret_cast<float2*>(ws_f + OFF_H2)[row] = make_float2(p0, p1);
    }
}

// ---------------- D2: g1 gather + g2 sliced gather (int4 deg build) -------------
// roles: [0,85) g1 node blocks | [85, 85+NS) g2 slice blocks
constexpr int K2_GRID = cN1 + NS;   // 175

__global__ __launch_bounds__(256) void k2_gather(
    const int* __restrict__ ei1, const int* __restrict__ ei2,
    float* __restrict__ ws_f)
{
    __shared__ float          s_acc[2 * PBINS];       // 45 KB
    __shared__ unsigned short s_deg[PBINS];           // 11 KB
    int b = blockIdx.x, t = threadIdx.x;

    if (b < cN1) {
        // graph1 node b: parallel match scan -> LDS list -> register accumulate
        int* s_list = reinterpret_cast<int*>(s_acc);  // [0]=count, [1..]=srcs
        if (t == 0) s_list[0] = 0;
        __syncthreads();
        for (int i = t; i < cE1; i += 256) {          // 6 coalesced iterations
            int d = ei1[cE1 + i];
            if (d == b) {
                int k = atomicAdd(&s_list[0], 1) + 1;
                s_list[k] = ei1[i];
            }
        }
        __syncthreads();
        int cnt = s_list[0];
        if (t < cO1) {
            float acc = 0.f;
            for (int m = 1; m <= cnt; ++m) {          // ~16 iters, indep loads
                int s = s_list[m];
                acc = fmaf(ws_f[OFF_DINV1 + s], ws_f[OFF_H1 + s * cO1 + t], acc);
            }
            float dn = ws_f[OFF_DINV1 + b];
            ws_f[OFF_G1 + b * cO1 + t] =
                dn * (acc + dn * ws_f[OFF_H1 + b * cO1 + t]);
        }
        return;
    }
    int s = b - cN1;
    const int4* part4 = reinterpret_cast<const int4*>(
        reinterpret_cast<const int*>(ws_f) + OFF_PART);

    // Build u16 deg table from the 4 partials with int4 loads (6 wide rounds).
    for (int g = t; g < PBINS / 4; g += 256) {
        int4 a = part4[g];
        int4 c = part4[(PBINS / 4) + g];
        int4 d = part4[2 * (PBINS / 4) + g];
        int4 e = part4[3 * (PBINS / 4) + g];
        s_deg[4 * g + 0] = (unsigned short)(a.x + c.x + d.x + e.x);
        s_deg[4 * g + 1] = (unsigned short)(a.y + c.y + d.y + e.y);
        s_deg[4 * g + 2] = (unsigned short)(a.z + c.z + d.z + e.z);
        s_deg[4 * g + 3] = (unsigned short)(a.w + c.w + d.w + e.w);
    }
    for (int i = t; i < 2 * PBINS; i += 256) s_acc[i] = 0.f;
    __syncthreads();

    // Branch-free int4-batched scan; dinv[src] inline via LDS deg + rsqrt.
    const int e0 = s * ESL;
    const float2* h2 = reinterpret_cast<const float2*>(ws_f + OFF_H2);
    #pragma unroll
    for (int batch = 0; batch < 2; ++batch) {
        int off = batch * 1024 + t * 4;
        if (off < ESL) {                              // int4 fully valid (4 | ESL)
            int4 s4 = *reinterpret_cast<const int4*>(ei2 + e0 + off);
            int4 d4 = *reinterpret_cast<const int4*>(ei2 + cE2 + e0 + off);
            float2 ha = h2[s4.x], hb = h2[s4.y], hc = h2[s4.z], hd = h2[s4.w];
            float v0 = rsqrtf((float)(s_deg[s4.x] + 1));
            float v1 = rsqrtf((float)(s_deg[s4.y] + 1));
            float v2 = rsqrtf((float)(s_deg[s4.z] + 1));
            float v3 = rsqrtf((float)(s_deg[s4.w] + 1));
            atomicAdd(&s_acc[d4.x * 2 + 0], ha.x * v0);
            atomicAdd(&s_acc[d4.x * 2 + 1], ha.y * v0);
            atomicAdd(&s_acc[d4.y * 2 + 0], hb.x * v1);
            atomicAdd(&s_acc[d4.y * 2 + 1], hb.y * v1);
            atomicAdd(&s_acc[d4.z * 2 + 0], hc.x * v2);
            atomicAdd(&s_acc[d4.z * 2 + 1], hc.y * v2);
            atomicAdd(&s_acc[d4.w * 2 + 0], hd.x * v3);
            atomicAdd(&s_acc[d4.w * 2 + 1], hd.y * v3);
        }
    }
    __syncthreads();
    float* dst = ws_f + OFF_P2 + s * PBINS * 2;
    for (int i = t; i < 2 * PBINS; i += 256) dst[i] = s_acc[i];   // coalesced
}

// ---------------- D3: parallel partial-reduce + bias + relu + final linear ------
__global__ __launch_bounds__(128) void k3_head(
    const float* __restrict__ ws_f,
    const float* __restrict__ b1, const float* __restrict__ b2,
    const float* __restrict__ Wf, const float* __restrict__ bf,
    float* __restrict__ out)
{
    const int* ws_i = reinterpret_cast<const int*>(ws_f);
    __shared__ float sred[45][2];
    __shared__ float sh[113];
    int r = blockIdx.x, t = threadIdx.x;

    // Phase A: reduce the NS=90 g2 partials; 2 threads per (n,c) target.
    if (t < 90) {
        int j = t >> 1, half = t & 1;
        int f = r * 45 + j, n = f >> 1, c = f & 1;
        const float* base = ws_f + OFF_P2 + n * 2 + c;
        float s = 0.f;
        #pragma unroll 9
        for (int p = half * 45; p < half * 45 + 45; ++p)
            s += base[p * PBINS * 2];
        sred[j][half] = s;
    }
    __syncthreads();

    // Phase B: assemble the 113-wide concat row (bias + relu).
    if (t < 113) {
        float v;
        if (t < 68) {
            int f = r * 68 + t;                       // h1.reshape(250,68) flat
            v = ws_f[OFF_G1 + f] + b1[f % 200];
        } else {
            int j = t - 68;
            int f = r * 45 + j, n = f >> 1, c = f & 1;
            int d = 0;
            #pragma unroll
            for (int p = 0; p < NPART; ++p) d += ws_i[OFF_PART + p * PBINS + n];
            float dv = rsqrtf((float)(d + 1));
            float sum = sred[j][0] + sred[j][1];
            v = dv * sum + dv * dv * ws_f[OFF_H2 + n * 2 + c] + b2[c];
        }
        sh[t] = fmaxf(v, 0.f);
    }
    __syncthreads();

    // Phase C: final 113x5 linear; 5 outputs x 16-lane shuffle groups.
    if (t < 80) {
        int o = t >> 4, l = t & 15;
        float s = 0.f;
        for (int k = l; k < 113; k += 16)
            s = fmaf(sh[k], Wf[k * 5 + o], s);
        #pragma unroll
        for (int m = 8; m >= 1; m >>= 1) s += __shfl_down(s, m, 16);
        if (l == 0) out[r * 5 + o] = s + bf[o];
    }
}

extern "C" void kernel_launch(void* const* d_in, const int* in_sizes, int n_in,
                              void* d_out, int out_size, void* d_ws, size_t ws_size,
                              hipStream_t stream)
{
    const float* x1 = (const float*)d_in[0];
    const float* x2 = (const float*)d_in[1];
    const float* W1 = (const float*)d_in[2];
    const float* b1 = (const float*)d_in[3];
    const float* W2 = (const float*)d_in[4];
    const float* b2 = (const float*)d_in[5];
    const float* Wf = (const float*)d_in[6];
    const float* bf = (const float*)d_in[7];
    const int*   ei1 = (const int*)d_in[8];
    const int*   ei2 = (const int*)d_in[9];
    float* ws_f = (float*)d_ws;
    float* out  = (float*)d_out;

    k1_front<<<K1_GRID, 256, 0, stream>>>(x1, x2, W1, W2, ei1, ei2, ws_f);
    k2_gather<<<K2_GRID, 256, 0, stream>>>(ei1, ei2, ws_f);
    k3_head<<<250, 128, 0, stream>>>(ws_f, b1, b2, Wf, bf, out);
}